// Round 1
// 125.301 us; speedup vs baseline: 1.0714x; 1.0714x over previous
//
#include <hip/hip_runtime.h>
#include <math.h>

#define B_ 8
#define N_ 1024
#define M_ 20000
#define C_ 80
#define G_ 64
typedef unsigned long long ull;

// ws: boxes [B][1024]float4 (128KB) | meta [B][1024]float2 (64KB) | adj [B][1024][16]ull (1MB)
#define WS_BOX_OFF  0
#define WS_META_OFF 131072
#define WS_ADJ_OFF  262144

__device__ __forceinline__ float iou1(float ax, float ay, float az, float aw,
                                      float bx, float by, float bz, float bw) {
    // legacy +1 convention, exact reference arithmetic order
    float lx = fmaxf(ax, bx), ly = fmaxf(ay, by);
    float rx = fminf(az, bz), ry = fminf(aw, bw);
    float w = fmaxf(rx - lx + 1.0f, 0.0f), h = fmaxf(ry - ly + 1.0f, 0.0f);
    float ov = w * h;
    float a1 = (az - ax + 1.0f) * (aw - ay + 1.0f);
    float a2 = (bz - bx + 1.0f) * (bw - by + 1.0f);
    return ov / (a1 + a2 - ov);
}

// ---- K1: scores + hybrid bitonic sort (double-buffered LDS stages) + SoA tables ----
__global__ __launch_bounds__(1024) void prep_kernel(
    const int* __restrict__ pos_inds, const int* __restrict__ pos_gt,
    const float* __restrict__ bbox_preds, const float* __restrict__ cls_scores,
    const int* __restrict__ gt_labels, float4* __restrict__ boxesG,
    float2* __restrict__ metaG, float* __restrict__ out) {
    const int b = blockIdx.x, t = threadIdx.x;
    __shared__ ull s_k2[2][N_];   // 16 KB: A/B buffers -> 1 barrier per LDS stage

    if (b == 0 && t == 0) { out[0] = 0.f; out[1] = 0.f; }  // init before sweep_loss

    int g0 = pos_gt[b * N_ + t];
    int lab = gt_labels[b * G_ + g0];
    int pi = pos_inds[b * N_ + t];
    float s = cls_scores[(size_t)b * (M_ * C_) + (size_t)pi * C_ + lab];
    // descending score, tie -> ascending original index (jnp.argmax tie-break)
    ull key = ((ull)(~__float_as_uint(s)) << 32) | (unsigned)t;

    int pb = 0;
    for (unsigned k2 = 2; k2 <= N_; k2 <<= 1) {
        for (unsigned jj = k2 >> 1; jj; jj >>= 1) {
            ull other;
            if (jj >= 64) {   // cross-wave: alternating buffers, single barrier
                s_k2[pb][t] = key;
                __syncthreads();
                other = s_k2[pb][t ^ jj];
                pb ^= 1;
            } else {          // intra-wave: register shfl, no barrier
                int lo = __shfl_xor((int)(unsigned)key, (int)jj);
                int hi = __shfl_xor((int)(unsigned)(key >> 32), (int)jj);
                other = ((ull)(unsigned)hi << 32) | (unsigned)lo;
            }
            bool keep_min = (((t & jj) == 0) == ((t & k2) == 0));
            ull mn = key < other ? key : other;
            ull mx = key < other ? other : key;
            key = keep_min ? mn : mx;
        }
    }

    int j = (int)(unsigned)(key & 0xFFFFFFFFull);
    float ss = __uint_as_float(~(unsigned)(key >> 32));   // exact score recovery
    const float* bp = bbox_preds + (size_t)(b * N_ + j) * 4;
    float x0 = bp[0], y0 = bp[1], x1 = bp[2], y1 = bp[3];
    int g = pos_gt[b * N_ + j];
    boxesG[b * N_ + t] = make_float4(x0, y0, x1, y1);
    metaG[b * N_ + t] = make_float2(__int_as_float(g), ss);
}

// ---- K2: TRIANGULAR adjacency, coalesced SoA loads + ballot word packing ----
// word u, bit p of row r  <=>  iou(r, 64u+p) > 0.5  (identical layout to prior u16 packing)
__global__ __launch_bounds__(256) void adj_kernel(
    const float4* __restrict__ boxesG, ull* __restrict__ adjG) {
    const int b = blockIdx.y;
    const int r = blockIdx.x * 4 + (threadIdx.x >> 6);
    const int lane = threadIdx.x & 63;
    const int wtop = r >> 6;
    const float4* bb = boxesG + (size_t)b * N_;
    float4 rA = bb[r];
    float ax0 = rA.x, ay0 = rA.y;
    float az1 = rA.z + 1.0f, aw1 = rA.w + 1.0f;
    float a1 = (rA.z - rA.x + 1.0f) * (rA.w - rA.y + 1.0f);
    ull myword = 0ull;
    for (int u = 0; u <= wtop; ++u) {   // wave-uniform trip count (r uniform per wave)
        float4 cA = bb[u * 64 + lane];  // 16B/lane, fully coalesced
        float lx = fmaxf(ax0, cA.x), ly = fmaxf(ay0, cA.y);
        float rx = fminf(az1, cA.z + 1.0f), ry = fminf(aw1, cA.w + 1.0f);
        float w = fmaxf(rx - lx, 0.0f), h = fmaxf(ry - ly, 0.0f);
        float I = w * h;
        float a2 = (cA.z - cA.x + 1.0f) * (cA.w - cA.y + 1.0f);
        ull word = __ballot(3.0f * I > a1 + a2);   // iou>0.5 <=> 3I > a1+a2
        if (lane == u) myword = word;
    }
    if (lane <= wtop) adjG[(size_t)(b * N_ + r) * 16 + lane] = myword;
}

// ---- K3: fused sweep (symmetric-adjacency batched-round acceptance) + loss ----
__global__ __launch_bounds__(1024) void sweep_loss_kernel(
    const float4* __restrict__ boxesG, const float2* __restrict__ metaG,
    const ull* __restrict__ adjG, const float* __restrict__ gt_bboxes,
    float* __restrict__ out) {
    const int b = blockIdx.x, t = threadIdx.x;
    const int wtop = t >> 6, lane = t & 63;

    __shared__ float4 s_box[N_];           // 16 KB
    __shared__ float s_score[N_];          // 4 KB
    __shared__ short s_g[N_];              // 2 KB
    __shared__ float4 s_gt[G_];            // 1 KB: staged gt boxes
    __shared__ ull s_S[16];                // survivor bitmask
    __shared__ unsigned short s_step[N_];  // position -> rank
    __shared__ unsigned short s_surv[N_];  // rank -> position
    __shared__ float s_ts[N_];             // per-step push sums
    __shared__ int s_cnt[N_], s_kills[N_], s_first[G_];
    __shared__ int s_wpre[17];
    __shared__ float s_tpull, s_tpush;
    __shared__ int s_pcnt, s_qcnt;

    {   // stage elements + init
        float4 bx = boxesG[b * N_ + t];
        float2 mt = metaG[b * N_ + t];
        s_box[t] = bx; s_score[t] = mt.y; s_g[t] = (short)__float_as_int(mt.x);
    }
    if (t < G_) s_gt[t] = ((const float4*)gt_bboxes)[b * G_ + t];
    s_ts[t] = 0.f; s_cnt[t] = 0; s_kills[t] = 0; s_step[t] = 0xffff;
    if (t < 16) s_S[t] = 0ull;
    if (t < G_) s_first[t] = 0x7fffffff;
    if (t == 0) { s_tpull = 0.f; s_tpush = 0.f; s_pcnt = 0; s_qcnt = 0; }

    // my adjacency row words for chunks <= mine (bit q of word c = adj(t, 64c+q))
    const ull* rowp = adjG + (size_t)(b * N_ + t) * 16;
    ull rw[16];
#pragma unroll
    for (int c = 0; c < 16; ++c) rw[c] = (c <= wtop) ? rowp[c] : 0ull;

    __syncthreads();

    // ---- sweep: 16 ordered chunk phases; acceptance rounds use ADJACENCY SYMMETRY:
    //   killed_j <=> exists i in U with adj(i,j) <=> (myearly_j & U) != 0
    //   (above-diagonal bits of row_j can never hit U: such i would have an earlier
    //    alive neighbor j and thus not be in U) -> no cross-lane OR-reduce needed.
    bool alive_f = true;
#pragma unroll
    for (int c = 0; c < 16; ++c) {
        if (wtop == c) {   // wave-uniform; whole wave active
            ull alive = __ballot(alive_f);
            ull Sc = 0ull;
            const ull below = (1ull << lane) - 1ull;     // lane 0 -> 0
            const ull myearly = rw[c] & below;           // earlier in-chunk neighbors
            while (alive) {
                bool me = (alive >> lane) & 1ull;
                bool inU = me && ((myearly & alive) == 0ull);
                ull U = __ballot(inU);
                Sc |= U;
                alive = __ballot(me && !inU && ((myearly & U) == 0ull));
            }
            if (lane == 0) s_S[c] = Sc;
        }
        __syncthreads();
        if (wtop > c && alive_f && (rw[c] & s_S[c]) != 0ull) alive_f = false;
    }

    // ---- survivor ranks (pop order = ascending position, proven monotone) ----
    if (t < 16) s_wpre[t + 1] = __popcll(s_S[t]);
    __syncthreads();
    if (t == 0) { s_wpre[0] = 0; for (int w = 0; w < 16; ++w) s_wpre[w + 1] += s_wpre[w]; }
    __syncthreads();
    const int K = s_wpre[16];
    const ull sbit = 1ull << lane;
    const bool isS = (s_S[wtop] & sbit) != 0ull;
    int myrank = -1;
    if (isS) {
        myrank = s_wpre[wtop] + __popcll(s_S[wtop] & (sbit - 1ull));
        s_step[t] = (unsigned short)myrank;
        s_surv[myrank] = (unsigned short)t;
        atomicMin(&s_first[(int)s_g[t]], myrank);
    }
    __syncthreads();

    // ---- suppressed j: killer = first adjacent survivor below j ----
    if (!isS) {
        int kp = -1;
#pragma unroll
        for (int w = 15; w >= 0; --w) {   // descending so final = lowest word hit
            ull m = rw[w] & s_S[w];       // rw[w]=0 for w>wtop
            if (w == wtop) m &= (1ull << lane) - 1ull;
            if (m) kp = (w << 6) + (int)(__ffsll(m) - 1);
        }
        if (kp >= 0) {   // always true: every non-survivor has a killer
            int q = s_step[kp];
            atomicAdd(&s_kills[q], 1);   // 'remaining' evidence
            int gq = (int)s_g[kp], gj = (int)s_g[t];
            if (gq != gj) {
                float4 qa = s_box[kp], ja = s_box[t];
                float ov = iou1(qa.x, qa.y, qa.z, qa.w, ja.x, ja.y, ja.z, ja.w);
                float4 gq4 = s_gt[gq], gj4 = s_gt[gj];
                float gov = iou1(gq4.x, gq4.y, gq4.z, gq4.w,
                                 gj4.x, gj4.y, gj4.z, gj4.w);
                if (ov > gov) {
                    atomicAdd(&s_cnt[q], 1);
                    atomicAdd(&s_ts[q], -__logf(1.0f - ov) * s_score[t]);
                }
            }
        }
    }
    __syncthreads();

    // ---- pull per survivor + per-step push normalization ----
    if (isS) {
        int k = myrank, g = (int)s_g[t], f = s_first[g];
        if (f < k) {
            atomicAdd(&s_pcnt, 1);   // NOT gated on remaining (matches reference)
            // pull dropped iff last pop and it kills nobody (remaining == false)
            bool drop = (k == K - 1) && (s_kills[k] == 0);
            if (!drop) {
                float4 fA = s_box[s_surv[f]], kA = s_box[t];
                float ov = iou1(fA.x, fA.y, fA.z, fA.w, kA.x, kA.y, kA.z, kA.w);
                atomicAdd(&s_tpull, -__logf(0.5f + fmaxf(ov, 1e-6f)) * s_score[t]);
            }
        }
        if (s_cnt[k] > 0) {   // cnt>0 => kills>0 => remaining true
            atomicAdd(&s_tpush, s_ts[k] / (float)s_cnt[k]);
            atomicAdd(&s_qcnt, s_cnt[k]);
        }
    }
    __syncthreads();

    if (t == 0) {
        atomicAdd(&out[0], (s_tpush / ((float)s_qcnt + 1e-6f)) * 0.125f);  // mean push, B=8
        atomicAdd(&out[1], (s_tpull / ((float)s_pcnt + 1e-6f)) * 0.125f);  // mean pull
    }
}

extern "C" void kernel_launch(void* const* d_in, const int* in_sizes, int n_in,
                              void* d_out, int out_size, void* d_ws, size_t ws_size,
                              hipStream_t stream) {
    const int* pos_inds = (const int*)d_in[0];
    const int* pos_gt = (const int*)d_in[1];
    const float* gt_bboxes = (const float*)d_in[2];
    const float* bbox_preds = (const float*)d_in[3];
    const float* cls_scores = (const float*)d_in[4];
    const int* gt_labels = (const int*)d_in[5];
    float* out = (float*)d_out;

    float4* boxesG = (float4*)((char*)d_ws + WS_BOX_OFF);
    float2* metaG = (float2*)((char*)d_ws + WS_META_OFF);
    ull* adjG = (ull*)((char*)d_ws + WS_ADJ_OFF);

    // out zero-init folded into prep_kernel (prep fully precedes sweep_loss on stream)
    prep_kernel<<<dim3(B_), dim3(1024), 0, stream>>>(
        pos_inds, pos_gt, bbox_preds, cls_scores, gt_labels, boxesG, metaG, out);
    adj_kernel<<<dim3(256, B_), dim3(256), 0, stream>>>(boxesG, adjG);
    sweep_loss_kernel<<<dim3(B_), dim3(1024), 0, stream>>>(boxesG, metaG, adjG, gt_bboxes, out);
}